// Round 10
// baseline (342.954 us; speedup 1.0000x reference)
//
#include <hip/hip_runtime.h>
#include <cstdint>
#include <cstddef>

typedef _Float16 f16;
typedef __attribute__((ext_vector_type(4)))  _Float16 f16x4;
typedef __attribute__((ext_vector_type(8)))  _Float16 f16x8;
typedef __attribute__((ext_vector_type(2)))  __fp16   fp16v2;
typedef __attribute__((ext_vector_type(4)))  float    f32x4;
typedef __attribute__((ext_vector_type(16))) float    f32x16;

static constexpr int BB = 16, LL = 2048, DIN = 512, HH = 256, DOUT = 1024;
static constexpr float SCALE = 0.0625f;   // 1/sqrt(256)
#define NEG_BIG (-1e30f)

#define BAR()    __builtin_amdgcn_s_barrier()
#define SCHED0() __builtin_amdgcn_sched_barrier(0)

__device__ __forceinline__ void gload16(const void* g, void* l) {
  __builtin_amdgcn_global_load_lds(
      (const __attribute__((address_space(1))) unsigned int*)g,
      (__attribute__((address_space(3))) unsigned int*)l, 16, 0, 0);
}

__device__ __forceinline__ unsigned pk2(float a, float b) {
  union { fp16v2 v; unsigned u; } c;
  c.v = __builtin_amdgcn_cvt_pkrtz(a, b);
  return c.u;
}

// ---- both W transposes in one launch: W[512][256] f32 -> WT[256][512] f16
__global__ void wt2_kernel(const float* __restrict__ Wa, const float* __restrict__ Wb,
                           f16* __restrict__ WTa, f16* __restrict__ WTb) {
  int g = blockIdx.x * 256 + threadIdx.x;     // 262144 total
  const float* W = (g < 131072) ? Wa : Wb;
  f16* WT = (g < 131072) ? WTa : WTb;
  int gg = g & 131071;
  int d = gg >> 8, h = gg & 255;
  WT[h * 512 + d] = (f16)W[gg];
}

// ---- V transpose+cast: mem[b][m][512] f32 -> VT[b][512][2048] f16
__global__ void vt_kernel(const float* __restrict__ mem, f16* __restrict__ VT) {
  int m0 = blockIdx.x * 32, d0 = blockIdx.y * 32, b = blockIdx.z;
  __shared__ f16 t[32][36];                   // [d_local][m_local(+pad)]
  int tid = threadIdx.x;
  {
    int r = tid >> 3, c4 = (tid & 7) * 4;
    float4 v = *(const float4*)(mem + (size_t)(b * LL + m0 + r) * DIN + d0 + c4);
    t[c4 + 0][r] = (f16)v.x; t[c4 + 1][r] = (f16)v.y;
    t[c4 + 2][r] = (f16)v.z; t[c4 + 3][r] = (f16)v.w;
  }
  __syncthreads();
  {
    int d = tid >> 3, seg = tid & 7;
    f16x4 hv = *(const f16x4*)&t[d][seg * 4];
    *(f16x4*)(VT + (size_t)(b * 512 + d0 + d) * 2048 + m0 + seg * 4) = hv;
  }
}

// ---- projection (both in one launch, z selects): Out[M][256] = f16(relu(X * W))
__global__ __launch_bounds__(256, 2) void proj_kernel(const float* __restrict__ Xa,
                                                      const float* __restrict__ Xb,
                                                      const f16* __restrict__ WTa,
                                                      const f16* __restrict__ WTb,
                                                      f16* __restrict__ Oa,
                                                      f16* __restrict__ Ob) {
  const float* X = blockIdx.z ? Xb : Xa;
  const f16* WT  = blockIdx.z ? WTb : WTa;
  f16* Out       = blockIdx.z ? Ob : Oa;
  const int Rbase = blockIdx.x * 128, Cbase = blockIdx.y * 128;
  __shared__ f16 a_t[128 * 40];
  __shared__ f16 b_t[128 * 32];
  const int tid = threadIdx.x, lane = tid & 63, wave = tid >> 6;
  const int wr = wave >> 1, wc = wave & 1;
  const int l15 = lane & 15, g4 = lane >> 4;
  f32x4 acc[4][4] = {};
  for (int ks = 0; ks < 16; ++ks) {
    __syncthreads();
#pragma unroll
    for (int k = 0; k < 4; ++k) {
      int idx = k * 256 + tid;
      int row = idx >> 3, c4 = idx & 7;
      float4 v = *(const float4*)(X + (size_t)(Rbase + row) * 512 + ks * 32 + c4 * 4);
      f16x4 hv = { (f16)v.x, (f16)v.y, (f16)v.z, (f16)v.w };
      *(f16x4*)((char*)a_t + row * 80 + c4 * 8) = hv;
    }
#pragma unroll
    for (int i = 0; i < 2; ++i) {
      int o = i * 4096 + wave * 1024 + lane * 16;
      int r = o >> 6, cp = o & 63;
      gload16((const char*)WT + (size_t)(Cbase + r) * 1024 + ks * 64 + (cp ^ ((r & 3) << 4)),
              (char*)b_t + i * 4096 + wave * 1024);
    }
    __syncthreads();
    f16x8 af[4], bf[4];
#pragma unroll
    for (int mi = 0; mi < 4; ++mi) {
      int r = wr * 64 + mi * 16 + l15;
      af[mi] = *(const f16x8*)((const char*)a_t + r * 80 + g4 * 16);
    }
#pragma unroll
    for (int ni = 0; ni < 4; ++ni) {
      int r = wc * 64 + ni * 16 + l15;
      bf[ni] = *(const f16x8*)((const char*)b_t + r * 64 + ((g4 * 16) ^ ((r & 3) << 4)));
    }
#pragma unroll
    for (int mi = 0; mi < 4; ++mi)
#pragma unroll
      for (int ni = 0; ni < 4; ++ni)
        acc[mi][ni] = __builtin_amdgcn_mfma_f32_16x16x32_f16(af[mi], bf[ni], acc[mi][ni], 0, 0, 0);
  }
#pragma unroll
  for (int mi = 0; mi < 4; ++mi)
#pragma unroll
    for (int ni = 0; ni < 4; ++ni)
#pragma unroll
      for (int di = 0; di < 4; ++di) {
        int row = Rbase + wr * 64 + mi * 16 + g4 * 4 + di;
        int col = Cbase + wc * 64 + ni * 16 + l15;
        float v = acc[mi][ni][di];
        Out[(size_t)row * 256 + col] = (f16)(v > 0.f ? v : 0.f);
      }
}

// ---- flash attention: merged-phase schedule. Per iteration:
//   bar(WAR) -> stage(t+2) -> vmcnt(6) -> bar(ready) ->
//   MEGA { QK(t+1) || PV(t) interleaved } -> softmax(t+1) [register-only, no barrier]
// K double-buffer (2x16K), V 3-ring (3x32K), Msk 8K = 136 KB. 1 block/CU.
// Numerics identical to R3/R9 (shfl_xor, select-mask, defer-max THR=8).
__global__ __launch_bounds__(512, 2) void attn_kernel(
    const float* __restrict__ X, const int* __restrict__ mask,
    const f16* __restrict__ Qh, const f16* __restrict__ Kh,
    const f16* __restrict__ VT, float* __restrict__ out) {
  // XCD-bijective swizzle (256 = 8*32): XCD serves 2 whole batches
  const int bid = blockIdx.x;
  const int lb = ((bid & 7) << 5) | (bid >> 3);
  const int b = lb >> 4, qbase = (lb & 15) * 128;
  const int tid = threadIdx.x, lane = tid & 63, wave = tid >> 6;
  const int hi = lane >> 5, l31 = lane & 31;
  const int qsub = wave & 3, dvh = wave >> 2;
  __shared__ f16 KtBuf[2][32 * 256];   // rows 512 B, XOR((m&31)<<4)
  __shared__ f16 VtBuf[3][512 * 32];   // rows 64 B,  XOR(((dv>>1)&3)<<4)
  __shared__ int Msk[2048];

  // concat-copy: out[..., 512:1024] = inputs
#pragma unroll
  for (int k = 0; k < 32; ++k) {
    int f4 = k * 512 + tid;
    int row = f4 >> 7, c4 = f4 & 127;
    *(float4*)(out + (size_t)(b * LL + qbase + row) * DOUT + 512 + c4 * 4) =
        *(const float4*)(X + (size_t)(b * LL + qbase + row) * DIN + c4 * 4);
  }
  {
    int4 mv = *(const int4*)(mask + b * LL + tid * 4);
    *(int4*)&Msk[tid * 4] = mv;
  }
  const int qr = qbase + qsub * 32 + l31;
  f16x8 Qf[16];
  {
    const f16x8* qrow = (const f16x8*)(Qh + (size_t)(b * LL + qr) * HH);
#pragma unroll
    for (int c = 0; c < 16; ++c) Qf[c] = qrow[2 * c + hi];
  }
  f32x16 acc[8] = {};
  float m_run = NEG_BIG, l_run = 0.f;
  f16x8 pf[2];

  auto stageK = [&](int bufi, int mbase) {
#pragma unroll
    for (int i = 0; i < 2; ++i) {
      int o = i * 8192 + wave * 1024 + lane * 16;
      int r = o >> 9, cp = o & 511;
      gload16((const char*)Kh + (size_t)(b * LL + mbase + r) * 512 + (cp ^ ((r & 31) << 4)),
              (char*)KtBuf[bufi] + o);
    }
  };
  auto stageV = [&](int bufi, int mbase) {
#pragma unroll
    for (int i = 0; i < 4; ++i) {
      int o = i * 8192 + wave * 1024 + lane * 16;
      int dv = o >> 6, cp = o & 63;
      gload16((const char*)VT + (size_t)(b * 512 + dv) * 4096 + mbase * 2 + (cp ^ (((dv >> 1) & 3) << 4)),
              (char*)VtBuf[bufi] + o);
    }
  };

  // softmax on (s0,s1) for tile at mbase -> updates m_run,l_run,acc, builds pf
  auto SM = [&](f32x16 s0, f32x16 s1, int mbase) {
    f32x16 s;
#pragma unroll
    for (int r = 0; r < 16; ++r) s[r] = s0[r] + s1[r];
    float tmax = NEG_BIG;
#pragma unroll
    for (int c2 = 0; c2 < 4; ++c2) {
      int4 mk = *(const int4*)&Msk[mbase + c2 * 8 + hi * 4];
      float x;
      x = s[4*c2+0] * SCALE; s[4*c2+0] = mk.x ? x : NEG_BIG;
      x = s[4*c2+1] * SCALE; s[4*c2+1] = mk.y ? x : NEG_BIG;
      x = s[4*c2+2] * SCALE; s[4*c2+2] = mk.z ? x : NEG_BIG;
      x = s[4*c2+3] * SCALE; s[4*c2+3] = mk.w ? x : NEG_BIG;
      tmax = fmaxf(tmax, fmaxf(fmaxf(s[4*c2+0], s[4*c2+1]), fmaxf(s[4*c2+2], s[4*c2+3])));
    }
    tmax = fmaxf(tmax, __shfl_xor(tmax, 32, 64));
    if (__any(tmax > m_run + 8.f)) {   // defer-max (T13, THR=8)
      float mnew = fmaxf(m_run, tmax);
      float alpha = __expf(m_run - mnew);
      m_run = mnew;
      l_run *= alpha;
#pragma unroll
      for (int r = 0; r < 16; ++r) {
        float ar = __shfl(alpha, (r & 3) + 8 * (r >> 2) + 4 * hi, 32);
#pragma unroll
        for (int t = 0; t < 8; ++t) acc[t][r] *= ar;
      }
    }
    float tsum = 0.f;
#pragma unroll
    for (int r = 0; r < 16; ++r) {
      float e = __expf(s[r] - m_run);
      s[r] = e;
      tsum += e;
    }
    tsum += __shfl_xor(tsum, 32, 64);
    l_run += tsum;
#pragma unroll
    for (int j = 0; j < 2; ++j) {
      unsigned a0 = pk2(s[8*j+0], s[8*j+1]);
      unsigned a1 = pk2(s[8*j+2], s[8*j+3]);
      unsigned b0 = pk2(s[8*j+4], s[8*j+5]);
      unsigned b1 = pk2(s[8*j+6], s[8*j+7]);
      asm volatile("v_permlane32_swap_b32 %0, %1" : "+v"(a0), "+v"(b0));
      asm volatile("v_permlane32_swap_b32 %0, %1" : "+v"(a1), "+v"(b1));
      union { f16x8 v; unsigned u[4]; } un;
      un.u[0] = a0; un.u[1] = a1; un.u[2] = b0; un.u[3] = b1;
      pf[j] = un.v;
    }
  };

  // prologue: stage first two tiles fully, drain once, compute softmax(0)
  stageK(0, 0); stageK(1, 32);
  stageV(0, 0); stageV(1, 32);
  __syncthreads();   // drains prologue loads; Msk visible
  {
    f32x16 s0 = {}, s1 = {};
    const char* kb = (const char*)KtBuf[0];
#pragma unroll
    for (int c = 0; c < 8; ++c) {
      f16x8 kf0 = *(const f16x8*)(kb + l31 * 512 + (((2 * c) * 32 + hi * 16) ^ (l31 << 4)));
      f16x8 kf1 = *(const f16x8*)(kb + l31 * 512 + (((2 * c + 1) * 32 + hi * 16) ^ (l31 << 4)));
      s0 = __builtin_amdgcn_mfma_f32_32x32x16_f16(kf0, Qf[2 * c], s0, 0, 0, 0);
      s1 = __builtin_amdgcn_mfma_f32_32x32x16_f16(kf1, Qf[2 * c + 1], s1, 0, 0, 0);
    }
    SM(s0, s1, 0);
  }

  int vs = 0;   // V-ring slot holding V(t)
  for (int t = 0; t < 63; ++t) {
    // bar-pre (WAR): all waves done with K(t) [read last mega/prologue] and V(t-1)
    BAR(); SCHED0();
    stageK(t & 1, ((t + 2) & 63) * 32);
    int vstage = vs + 2; if (vstage >= 3) vstage -= 3;
    stageV(vstage, ((t + 2) & 63) * 32);
    // retire the 6 oldest = K(t+1),V(t+1); keep 6 newest (t+2) in flight
    asm volatile("s_waitcnt vmcnt(6)" ::: "memory");
    SCHED0(); BAR(); SCHED0();

    // MEGA: QK(t+1) || PV(t), interleaved
    const char* kb = (const char*)KtBuf[(t + 1) & 1];
    const char* vb = (const char*)VtBuf[vs];
    f32x16 s0 = {}, s1 = {};
#pragma unroll
    for (int c = 0; c < 8; ++c) {
      f16x8 kf0 = *(const f16x8*)(kb + l31 * 512 + (((2 * c) * 32 + hi * 16) ^ (l31 << 4)));
      f16x8 kf1 = *(const f16x8*)(kb + l31 * 512 + (((2 * c + 1) * 32 + hi * 16) ^ (l31 << 4)));
      s0 = __builtin_amdgcn_mfma_f32_32x32x16_f16(kf0, Qf[2 * c], s0, 0, 0, 0);
      s1 = __builtin_amdgcn_mfma_f32_32x32x16_f16(kf1, Qf[2 * c + 1], s1, 0, 0, 0);
      // two PV MFMAs (independent acc chains) fill QK's dependency stalls
      int i0 = 2 * c, i1 = 2 * c + 1;
      {
        int j = i0 >> 3, tt = i0 & 7;
        int dvl = dvh * 256 + tt * 32 + l31;
        f16x8 vf = *(const f16x8*)(vb + dvl * 64 + ((j * 32 + hi * 16) ^ (((dvl >> 1) & 3) << 4)));
        acc[tt] = __builtin_amdgcn_mfma_f32_32x32x16_f16(pf[j], vf, acc[tt], 0, 0, 0);
      }
      {
        int j = i1 >> 3, tt = i1 & 7;
        int dvl = dvh * 256 + tt * 32 + l31;
        f16x8 vf = *(const f16x8*)(vb + dvl * 64 + ((j * 32 + hi * 16) ^ (((dvl >> 1) & 3) << 4)));
        acc[tt] = __builtin_amdgcn_mfma_f32_32x32x16_f16(pf[j], vf, acc[tt], 0, 0, 0);
      }
    }
    // softmax(t+1): register-only (Msk region is read-only), overlaps stage flight
    SM(s0, s1, (t + 1) * 32);
    vs = vs + 1; if (vs == 3) vs = 0;
  }

  // final PV(63): V(63) ready since iter-62's vmcnt+barrier; slot vs = 63%3 = 0
  {
    const char* vb = (const char*)VtBuf[vs];
#pragma unroll
    for (int j = 0; j < 2; ++j)
#pragma unroll
      for (int tt = 0; tt < 8; ++tt) {
        int dvl = dvh * 256 + tt * 32 + l31;
        f16x8 vf = *(const f16x8*)(vb + dvl * 64 + ((j * 32 + hi * 16) ^ (((dvl >> 1) & 3) << 4)));
        acc[tt] = __builtin_amdgcn_mfma_f32_32x32x16_f16(pf[j], vf, acc[tt], 0, 0, 0);
      }
  }

  // epilogue: divide by l (per-q via shfl), store context
  float linv = 1.f / l_run;
  float lr[16];
#pragma unroll
  for (int r = 0; r < 16; ++r) lr[r] = __shfl(linv, (r & 3) + 8 * (r >> 2) + 4 * hi, 32);
#pragma unroll
  for (int t = 0; t < 8; ++t) {
    int dv = dvh * 256 + t * 32 + l31;
#pragma unroll
    for (int r = 0; r < 16; ++r) {
      int q = qbase + qsub * 32 + (r & 3) + 8 * (r >> 2) + 4 * hi;
      out[(size_t)(b * LL + q) * DOUT + dv] = acc[t][r] * lr[r];
    }
  }
}

extern "C" void kernel_launch(void* const* d_in, const int* in_sizes, int n_in,
                              void* d_out, int out_size, void* d_ws, size_t ws_size,
                              hipStream_t stream) {
  const float* inputs = (const float*)d_in[0];
  const float* memory = (const float*)d_in[1];
  const int*   mmask  = (const int*)d_in[2];
  const float* W_in   = (const float*)d_in[3];
  const float* W_mem  = (const float*)d_in[4];
  float* out = (float*)d_out;

  char* ws = (char*)d_ws;
  f16* Qh  = (f16*)ws;                          // 16 MB
  f16* Kh  = (f16*)(ws + (16u << 20));          // 16 MB
  f16* VT  = (f16*)(ws + (32u << 20));          // 32 MB
  f16* WTi = (f16*)(ws + (64u << 20));          // 256 KB
  f16* WTm = (f16*)(ws + (64u << 20) + (1u << 18));

  wt2_kernel<<<1024, 256, 0, stream>>>(W_in, W_mem, WTi, WTm);
  vt_kernel<<<dim3(64, 16, 16), 256, 0, stream>>>(memory, VT);
  proj_kernel<<<dim3(256, 2, 2), 256, 0, stream>>>(inputs, memory, WTi, WTm, Qh, Kh);
  attn_kernel<<<256, 512, 0, stream>>>(inputs, mmask, Qh, Kh, VT, out);
}